// Round 1
// baseline (182.233 us; speedup 1.0000x reference)
//
#include <hip/hip_runtime.h>
#include <math.h>

#define H 128
#define MROWS 64           // node rows per MLP block
#define XS 136             // padded row stride (ushorts) for bf16 LDS tiles
#define NB 8               // buckets per side (c and r)
#define NB2 64             // NB*NB

typedef __attribute__((ext_vector_type(8))) short short8;
typedef __attribute__((ext_vector_type(4))) float floatx4;

__device__ __forceinline__ unsigned short f2bf(float f) {
    unsigned u = __float_as_uint(f);
    return (unsigned short)((u + 0x7FFFu + ((u >> 16) & 1u)) >> 16);  // RNE
}

__device__ __forceinline__ int bkt(int c, float s8) {
    int b = (int)((float)c * s8);          // s8 = NB/N; same formula in hist+scatter
    return b > (NB - 1) ? (NB - 1) : b;
}

// ---------------------------------------------------------------------------
// Kernel 0: W1,W2 fp32 -> bf16 once; also zero the 64 bucket counters.
// ---------------------------------------------------------------------------
__global__ void prep_weights(const float* __restrict__ W1,
                             const float* __restrict__ W2,
                             unsigned short* __restrict__ Wbf,
                             unsigned* __restrict__ cnt) {
    if (blockIdx.x == 0 && threadIdx.x < NB2) cnt[threadIdx.x] = 0;
    int i = blockIdx.x * 256 + threadIdx.x;       // 32768 total
    if (i < 16384)       Wbf[i] = f2bf(W1[i]);
    else if (i < 32768)  Wbf[i] = f2bf(W2[i - 16384]);
}

// ---------------------------------------------------------------------------
// Kernel 1: histogram of edges into 64 (c-bucket, r-bucket) bins.
// ---------------------------------------------------------------------------
__global__ __launch_bounds__(256) void hist_k(const int* __restrict__ ei, int E,
                                              float s8, unsigned* __restrict__ cnt) {
    __shared__ unsigned h[NB2];
    if (threadIdx.x < NB2) h[threadIdx.x] = 0;
    __syncthreads();
    const int stride = gridDim.x * 256;
    for (int e = blockIdx.x * 256 + threadIdx.x; e < E; e += stride) {
        int c = ei[e], r = ei[e + E];
        atomicAdd(&h[bkt(c, s8) * NB + bkt(r, s8)], 1u);
    }
    __syncthreads();
    if (threadIdx.x < NB2 && h[threadIdx.x])
        atomicAdd(&cnt[threadIdx.x], h[threadIdx.x]);
}

// ---------------------------------------------------------------------------
// Kernel 2: exclusive scan of 64 counters -> bucket bases + scatter cursors.
// ---------------------------------------------------------------------------
__global__ void scan_k(const unsigned* __restrict__ cnt,
                       unsigned* __restrict__ bb, unsigned* __restrict__ cur) {
    if (threadIdx.x == 0) {
        unsigned acc = 0;
        for (int i = 0; i < NB2; ++i) { bb[i] = acc; cur[i] = acc; acc += cnt[i]; }
        bb[NB2] = acc;                      // == E
    }
}

// ---------------------------------------------------------------------------
// Kernel 3: scatter edges into bucket-sorted list (c|r<<16, eidx).
// Block-aggregated ranks -> one global atomic per (block,bucket).
// ---------------------------------------------------------------------------
__global__ __launch_bounds__(256) void scatter_k(const int* __restrict__ ei, int E,
                                                 float s8, unsigned* __restrict__ cur,
                                                 uint2* __restrict__ lst) {
    __shared__ unsigned h[NB2];
    __shared__ unsigned base_s[NB2];
    const int nchunk = (E + 255) >> 8;
    for (int ch = blockIdx.x; ch < nchunk; ch += gridDim.x) {
        if (threadIdx.x < NB2) h[threadIdx.x] = 0;
        __syncthreads();
        const int e = ch * 256 + threadIdx.x;
        const bool v = e < E;
        int c = 0, r = 0, b = 0; unsigned rank = 0;
        if (v) {
            c = ei[e]; r = ei[e + E];
            b = bkt(c, s8) * NB + bkt(r, s8);
            rank = atomicAdd(&h[b], 1u);
        }
        __syncthreads();
        if (threadIdx.x < NB2 && h[threadIdx.x])
            base_s[threadIdx.x] = atomicAdd(&cur[threadIdx.x], h[threadIdx.x]);
        __syncthreads();
        if (v)
            lst[base_s[b] + rank] =
                make_uint2((unsigned)c | ((unsigned)r << 16), (unsigned)e);
        __syncthreads();                    // base_s reused next chunk
    }
}

// ---------------------------------------------------------------------------
// Kernel 4: g = mlp(emb); epilogue fully in registers; qtab stored in the
// dot-invariant column permutation col' = l15*8 + nt (8 contiguous bytes/lane).
// ---------------------------------------------------------------------------
__global__ __launch_bounds__(256, 2) void mlp_mfma(
    const float* __restrict__ emb, const unsigned short* __restrict__ Wbf,
    const float* __restrict__ b1, const float* __restrict__ b2,
    signed char* __restrict__ qtab, float* __restrict__ scl, int N)
{
    __shared__ unsigned short Wl[H * XS];         // 34 KB, W1 then W2
    __shared__ unsigned short xs[MROWS * XS];     // 17 KB
    __shared__ unsigned short hs[MROWS * XS];     // 17 KB

    const int tid   = threadIdx.x;
    const int wave  = tid >> 6, lane = tid & 63;
    const int quad  = lane >> 4, l15 = lane & 15;
    const int node0 = blockIdx.x * MROWS;

    // ---- stage W1 (bf16, row-padded) ----
    {
        const float4* src = (const float4*)Wbf;
        #pragma unroll
        for (int i = 0; i < 8; ++i) {
            int cc = i * 256 + tid;
            int row = cc >> 4, c = cc & 15;
            *(float4*)(Wl + row * XS + c * 8) = src[cc];
        }
    }
    // ---- stage x rows (fp32 -> bf16) ----
    #pragma unroll
    for (int i = 0; i < 8; ++i) {
        int flat = i * 1024 + tid * 4;
        int rowl = flat >> 7, col = flat & 127;
        float4 v = make_float4(0.f, 0.f, 0.f, 0.f);
        if (node0 + rowl < N)
            v = *(const float4*)(emb + (size_t)(node0 + rowl) * H + col);
        ushort4 b;
        b.x = f2bf(v.x); b.y = f2bf(v.y); b.z = f2bf(v.z); b.w = f2bf(v.w);
        *(ushort4*)(xs + rowl * XS + col) = b;
    }
    __syncthreads();

    const int mrow = wave * 16 + l15;
    short8 afr[4];

    // ---- layer 1: hs = elu(x @ W1^T + b1) ----
    #pragma unroll
    for (int ks = 0; ks < 4; ++ks)
        afr[ks] = *(const short8*)(xs + mrow * XS + ks * 32 + quad * 8);
    #pragma unroll
    for (int nt = 0; nt < 8; ++nt) {
        floatx4 acc = {0.f, 0.f, 0.f, 0.f};
        #pragma unroll
        for (int ks = 0; ks < 4; ++ks) {
            short8 bfr = *(const short8*)(Wl + (nt * 16 + l15) * XS + ks * 32 + quad * 8);
            acc = __builtin_amdgcn_mfma_f32_16x16x32_bf16(afr[ks], bfr, acc, 0, 0, 0);
        }
        const int col = nt * 16 + l15;
        const float bb1 = b1[col];
        #pragma unroll
        for (int r = 0; r < 4; ++r) {
            float v = acc[r] + bb1;
            v = v > 0.f ? v : (__expf(v) - 1.f);  // ELU
            hs[(wave * 16 + quad * 4 + r) * XS + col] = f2bf(v);
        }
    }
    __syncthreads();                              // hs done; all W1 reads done

    // ---- A-frags for layer 2, then stage W2 over W1 ----
    #pragma unroll
    for (int ks = 0; ks < 4; ++ks)
        afr[ks] = *(const short8*)(hs + mrow * XS + ks * 32 + quad * 8);
    {
        const float4* src = (const float4*)(Wbf + 16384);
        #pragma unroll
        for (int i = 0; i < 8; ++i) {
            int cc = i * 256 + tid;
            int row = cc >> 4, c = cc & 15;
            *(float4*)(Wl + row * XS + c * 8) = src[cc];
        }
    }
    __syncthreads();

    // ---- layer 2 in registers: av[nt][r] = g, fused sum-sq and max-abs ----
    floatx4 av[8];
    float sq[4] = {0.f, 0.f, 0.f, 0.f};
    float am[4] = {0.f, 0.f, 0.f, 0.f};
    #pragma unroll
    for (int nt = 0; nt < 8; ++nt) {
        floatx4 acc = {0.f, 0.f, 0.f, 0.f};
        #pragma unroll
        for (int ks = 0; ks < 4; ++ks) {
            short8 bfr = *(const short8*)(Wl + (nt * 16 + l15) * XS + ks * 32 + quad * 8);
            acc = __builtin_amdgcn_mfma_f32_16x16x32_bf16(afr[ks], bfr, acc, 0, 0, 0);
        }
        const float bb2 = b2[nt * 16 + l15];
        #pragma unroll
        for (int r = 0; r < 4; ++r) {
            float v = acc[r] + bb2;
            av[nt][r] = v;
            sq[r] += v * v;
            am[r] = fmaxf(am[r], fabsf(v));
        }
    }
    // row reductions across the 16 l15 lanes (butterfly -> all lanes hold result)
    #pragma unroll
    for (int r = 0; r < 4; ++r) {
        float s = sq[r], a = am[r];
        #pragma unroll
        for (int m = 8; m; m >>= 1) {
            s += __shfl_xor(s, m);
            a = fmaxf(a, __shfl_xor(a, m));
        }
        sq[r] = s; am[r] = a;
    }
    // ---- quantize + store: lane owns 8 contiguous bytes at col' = l15*8+nt ----
    #pragma unroll
    for (int r = 0; r < 4; ++r) {
        const int row = wave * 16 + quad * 4 + r;
        const int G = node0 + row;
        if (G < N) {
            const float a = fmaxf(am[r], 1e-20f);
            if (l15 == 0) {
                float nn = sqrtf(sq[r]);
                if (nn < 1e-8f) nn = 1e-8f;
                scl[G] = a / (nn * 127.f);
            }
            const float qs = 127.f / a;
            unsigned pk0 = 0, pk1 = 0;
            #pragma unroll
            for (int nt = 0; nt < 4; ++nt) {
                int q = (int)rintf(av[nt][r] * qs);
                q = q > 127 ? 127 : (q < -127 ? -127 : q);
                pk0 |= ((unsigned)(q & 255)) << (8 * nt);
            }
            #pragma unroll
            for (int nt = 4; nt < 8; ++nt) {
                int q = (int)rintf(av[nt][r] * qs);
                q = q > 127 ? 127 : (q < -127 ? -127 : q);
                pk1 |= ((unsigned)(q & 255)) << (8 * (nt - 4));
            }
            *(uint2*)(qtab + (size_t)G * H + l15 * 8) = make_uint2(pk0, pk1);
        }
    }
}

// ---------------------------------------------------------------------------
// Kernel 5: bucket-ordered edge cosine. cb = blockIdx%8 pins each c-slice
// (0.8 MB) to one XCD's L2; blocks sweep r-buckets in lockstep.
// ---------------------------------------------------------------------------
__device__ __forceinline__ int dot4(unsigned a, unsigned b) {
    int s = 0;
    #pragma unroll
    for (int j = 0; j < 4; ++j)
        s += (int)((signed char)(a >> (8 * j))) * (int)((signed char)(b >> (8 * j)));
    return s;
}

__global__ __launch_bounds__(256) void edge_cos(
    const uint2* __restrict__ lst, const signed char* __restrict__ qtab,
    const float* __restrict__ scl, const unsigned* __restrict__ bb,
    float* __restrict__ out)
{
    const int cb   = blockIdx.x & (NB - 1);
    const int blk  = blockIdx.x >> 3;
    const int nblk = gridDim.x >> 3;
    const unsigned s0 = bb[cb * NB];
    const unsigned s1 = bb[cb * NB + NB];
    const int sub  = threadIdx.x & 7;
    const int slot = threadIdx.x >> 3;            // 32 edges / block-iter

    for (unsigned base = s0 + (unsigned)blk * 32u; base < s1;
         base += (unsigned)nblk * 32u) {
        const unsigned idx = base + (unsigned)slot;
        if (idx < s1) {
            const uint2 pe = lst[idx];
            const int c = (int)(pe.x & 0xFFFFu);
            const int r = (int)(pe.x >> 16);
            const uint4 ua = *(const uint4*)(qtab + (size_t)c * H + sub * 16);
            const uint4 ub = *(const uint4*)(qtab + (size_t)r * H + sub * 16);
            int s = dot4(ua.x, ub.x) + dot4(ua.y, ub.y)
                  + dot4(ua.z, ub.z) + dot4(ua.w, ub.w);
            #pragma unroll
            for (int m = 4; m; m >>= 1) s += __shfl_xor(s, m);
            if (sub == 0) {
                float vv = (float)s * scl[c] * scl[r];
                __builtin_nontemporal_store(vv, out + pe.y);
            }
        }
    }
}

// ---------------------------------------------------------------------------
extern "C" void kernel_launch(void* const* d_in, const int* in_sizes, int n_in,
                              void* d_out, int out_size, void* d_ws, size_t ws_size,
                              hipStream_t stream) {
    const float* emb = (const float*)d_in[0];
    const int*   ei  = (const int*)d_in[1];
    const float* W1  = (const float*)d_in[2];
    const float* b1  = (const float*)d_in[3];
    const float* W2  = (const float*)d_in[4];
    const float* b2  = (const float*)d_in[5];
    float*       out = (float*)d_out;

    const int N = in_sizes[0] / H;
    const int E = in_sizes[1] / 2;

    // workspace layout (N<65536 assumed for 16-bit index packing)
    unsigned short* Wbf  = (unsigned short*)d_ws;           // 64 KB
    signed char*    qtab = (signed char*)(Wbf + 32768);     // N*H int8
    float*          sclp = (float*)(qtab + (size_t)N * H);  // N fp32
    uint2*          lst  = (uint2*)(sclp + N);              // E * 8 B
    unsigned*       cnt  = (unsigned*)(lst + E);            // 64
    unsigned*       bb   = cnt + 64;                        // 65 (+pad)
    unsigned*       cur  = bb + 72;                         // 64

    const float s8 = (float)NB / (float)N;

    prep_weights<<<128, 256, 0, stream>>>(W1, W2, Wbf, cnt);
    hist_k<<<512, 256, 0, stream>>>(ei, E, s8, cnt);
    scan_k<<<1, 64, 0, stream>>>(cnt, bb, cur);
    scatter_k<<<1024, 256, 0, stream>>>(ei, E, s8, cur, lst);
    mlp_mfma<<<(N + MROWS - 1) / MROWS, 256, 0, stream>>>(emb, Wbf, b1, b2, qtab, sclp, N);
    edge_cos<<<2048, 256, 0, stream>>>(lst, qtab, sclp, bb, out);
}